// Round 1
// baseline (625.838 us; speedup 1.0000x reference)
//
#include <hip/hip_runtime.h>
#include <hip/hip_bf16.h>
#include <cstdint>

// Problem constants (B=2,S=4096,D=2048,E=8,SH=2,F=512,K=2)
#define TOKENS   8192
#define D_DIM    2048
#define F_DIM    512
#define NE       8
#define NSH      2
#define NZ       10      // 8 routed + 2 shared
#define OUT_ELEMS (TOKENS * D_DIM)

typedef __attribute__((ext_vector_type(8))) short bf16x8;
typedef __attribute__((ext_vector_type(4))) float f32x4;

__device__ __forceinline__ short f2bf(float f) {
  union { float f; uint32_t u; } v; v.f = f;
  uint32_t r = (v.u + 0x7fffu + ((v.u >> 16) & 1u)) >> 16;
  return (short)r;
}

__device__ __forceinline__ void gload_lds16(const void* g, void* l) {
  __builtin_amdgcn_global_load_lds(
      (const __attribute__((address_space(1))) unsigned int*)g,
      (__attribute__((address_space(3))) unsigned int*)l,
      16, 0, 0);
}

// ---------------- convert fp32 -> bf16 (vectorized, grid-stride) -------------
__global__ void k_convert(const float* __restrict__ in, short* __restrict__ out, int n4) {
  int i = blockIdx.x * blockDim.x + threadIdx.x;
  int stride = gridDim.x * blockDim.x;
  for (; i < n4; i += stride) {
    float4 v = ((const float4*)in)[i];
    short4 o;
    o.x = f2bf(v.x); o.y = f2bf(v.y); o.z = f2bf(v.z); o.w = f2bf(v.w);
    ((short4*)out)[i] = o;
  }
}

// ------------- transpose-convert fp32 (R,C) -> bf16 (C,R), batched -----------
// grid: (C/32, R/32, batch), block: (32, 8)
__global__ void k_transpose(const float* __restrict__ in, short* __restrict__ out,
                            int R, int C) {
  __shared__ float tile[32][33];
  int b = blockIdx.z;
  in  += (size_t)b * R * C;
  out += (size_t)b * R * C;
  int c0 = blockIdx.x * 32, r0 = blockIdx.y * 32;
  #pragma unroll
  for (int i = 0; i < 32; i += 8) {
    int r = r0 + threadIdx.y + i, c = c0 + threadIdx.x;
    tile[threadIdx.y + i][threadIdx.x] = in[(size_t)r * C + c];
  }
  __syncthreads();
  #pragma unroll
  for (int i = 0; i < 32; i += 8) {
    int c = c0 + threadIdx.y + i, r = r0 + threadIdx.x;
    out[(size_t)c * R + r] = f2bf(tile[threadIdx.x][threadIdx.y + i]);
  }
}

// ---------------- init counts ------------------------------------------------
__global__ void k_init(unsigned* __restrict__ counts) {
  if (threadIdx.x < 2) counts[threadIdx.x] = 0u;
}

// ---------------- router: wave-per-token, fp32, exact top-2 ------------------
__global__ __launch_bounds__(256) void k_router(
    const float* __restrict__ x, const float* __restrict__ rw,
    const float* __restrict__ rb, float* __restrict__ gates,
    unsigned* __restrict__ counts) {
  int wave = threadIdx.x >> 6;
  int lane = threadIdx.x & 63;
  int t = blockIdx.x * 4 + wave;
  const float* xr = x + (size_t)t * D_DIM;
  float acc[NE];
  #pragma unroll
  for (int e = 0; e < NE; e++) acc[e] = 0.f;
  for (int d = lane; d < D_DIM; d += 64) {
    float xv = xr[d];
    #pragma unroll
    for (int e = 0; e < NE; e++) acc[e] += xv * rw[e * D_DIM + d];
  }
  #pragma unroll
  for (int e = 0; e < NE; e++) {
    #pragma unroll
    for (int off = 32; off > 0; off >>= 1) acc[e] += __shfl_xor(acc[e], off);
  }
  if (lane == 0) {
    float lg[NE];
    #pragma unroll
    for (int e = 0; e < NE; e++) lg[e] = acc[e] + rb[e];
    int i0 = 0;
    #pragma unroll
    for (int e = 1; e < NE; e++) if (lg[e] > lg[i0]) i0 = e;   // first max wins
    int i1 = (i0 == 0) ? 1 : 0;
    #pragma unroll
    for (int e = 0; e < NE; e++) if (e != i0 && e != i1 && lg[e] > lg[i1]) i1 = e;
    float e1 = __expf(lg[i1] - lg[i0]);
    float inv = 1.f / (1.f + e1);
    float g0 = inv, g1 = e1 * inv;
    float row[NE];
    #pragma unroll
    for (int e = 0; e < NE; e++) row[e] = 0.f;
    row[i0] = g0; row[i1] = g1;
    #pragma unroll
    for (int e = 0; e < NE; e++) gates[t * NE + e] = row[e];
    // load-balance-loss counts (faithful slot-vs-id quirk): slot k, idx==k
    if (i0 == 0) atomicAdd(&counts[0], 1u);
    if (i1 == 1) atomicAdd(&counts[1], 1u);
  }
}

// ---------------- aux loss ---------------------------------------------------
__global__ void k_loss(const unsigned* __restrict__ counts, float* __restrict__ out_loss) {
  if (threadIdx.x == 0 && blockIdx.x == 0) {
    float p0 = (float)counts[0] / 16384.0f + 1e-8f;
    float p1 = (float)counts[1] / 16384.0f + 1e-8f;
    float rest = 6.0f * (1e-8f * logf(1e-8f));
    out_loss[0] = -(p0 * logf(p0) + p1 * logf(p1) + rest);
  }
}

// ---------------- GEMM1: H[z] = gelu(X @ W1[z] + b1[z]) * gate ---------------
// X: (8192,2048) bf16 row-major. W1t[z]: (512,2048) bf16 (n-major: [f][d]).
// grid (64, 4, 10), block 256. Tile 128x128, BK=64.
__global__ __launch_bounds__(256) void k_gemm1(
    const short* __restrict__ xb, const short* __restrict__ w1t,
    const float* __restrict__ eb1, const float* __restrict__ sb1,
    const float* __restrict__ gates, short* __restrict__ H) {
  const int z = blockIdx.z;
  const int bm = blockIdx.x, bn = blockIdx.y;
  __shared__ __align__(16) short As[128 * 64];
  __shared__ __align__(16) short Bs[128 * 64];
  const int tid = threadIdx.x;
  const int lane = tid & 63;
  const int wv = tid >> 6;
  const int wm = wv >> 1, wn = wv & 1;
  const short* Bbase = w1t + (size_t)z * F_DIM * D_DIM;

  f32x4 acc[4][4];
  #pragma unroll
  for (int m = 0; m < 4; m++)
    #pragma unroll
    for (int n = 0; n < 4; n++) acc[m][n] = (f32x4)(0.f);

  for (int k0 = 0; k0 < D_DIM; k0 += 64) {
    #pragma unroll
    for (int i = 0; i < 4; i++) {
      int id = i * 256 + tid;
      int row = id >> 3, coff = (id & 7) * 8;
      gload_lds16(xb    + (size_t)(bm * 128 + row) * D_DIM + k0 + coff, &As[id * 8]);
      gload_lds16(Bbase + (size_t)(bn * 128 + row) * D_DIM + k0 + coff, &Bs[id * 8]);
    }
    __syncthreads();
    #pragma unroll
    for (int kk = 0; kk < 64; kk += 32) {
      bf16x8 af[4], bfr[4];
      #pragma unroll
      for (int m = 0; m < 4; m++)
        af[m] = *(const bf16x8*)&As[(wm * 64 + m * 16 + (lane & 15)) * 64 + kk + (lane >> 4) * 8];
      #pragma unroll
      for (int n = 0; n < 4; n++)
        bfr[n] = *(const bf16x8*)&Bs[(wn * 64 + n * 16 + (lane & 15)) * 64 + kk + (lane >> 4) * 8];
      #pragma unroll
      for (int m = 0; m < 4; m++)
        #pragma unroll
        for (int n = 0; n < 4; n++)
          acc[m][n] = __builtin_amdgcn_mfma_f32_16x16x32_bf16(af[m], bfr[n], acc[m][n], 0, 0, 0);
    }
    __syncthreads();
  }

  const float* b1 = (z < NE) ? (eb1 + z * F_DIM) : (sb1 + (size_t)(z - NE) * F_DIM);
  short* Hout = H + (size_t)z * TOKENS * F_DIM;
  #pragma unroll
  for (int m = 0; m < 4; m++) {
    #pragma unroll
    for (int r = 0; r < 4; r++) {
      int row = bm * 128 + wm * 64 + m * 16 + (lane >> 4) * 4 + r;
      float g = (z < NE) ? gates[row * NE + z] : 1.0f;
      #pragma unroll
      for (int n = 0; n < 4; n++) {
        int col = bn * 128 + wn * 64 + n * 16 + (lane & 15);
        float c = acc[m][n][r] + b1[col];
        float h = 0.5f * c * (1.0f + erff(c * 0.70710678118654752440f));
        Hout[(size_t)row * F_DIM + col] = f2bf(h * g);
      }
    }
  }
}

// ---------------- GEMM2: out = sum_z H[z] @ W2t[z] + biases ------------------
// A: H (10,8192,512) bf16; B: w2t (10,2048,512) bf16 ([z][d][f]).
// K = 5120 (z-major, f within). grid (64,16), block 256.
__global__ __launch_bounds__(256) void k_gemm2(
    const short* __restrict__ H, const short* __restrict__ w2t,
    const float* __restrict__ eb2, const float* __restrict__ sb2,
    const float* __restrict__ gates, float* __restrict__ out) {
  const int bm = blockIdx.x, bn = blockIdx.y;
  __shared__ __align__(16) short As[128 * 64];
  __shared__ __align__(16) short Bs[128 * 64];
  const int tid = threadIdx.x;
  const int lane = tid & 63;
  const int wv = tid >> 6;
  const int wm = wv >> 1, wn = wv & 1;

  f32x4 acc[4][4];
  #pragma unroll
  for (int m = 0; m < 4; m++)
    #pragma unroll
    for (int n = 0; n < 4; n++) acc[m][n] = (f32x4)(0.f);

  for (int k0 = 0; k0 < NZ * F_DIM; k0 += 64) {
    const int z = k0 >> 9, f0 = k0 & 511;
    const short* Ab = H   + (size_t)z * TOKENS * F_DIM;
    const short* Bb = w2t + (size_t)z * D_DIM * F_DIM;
    #pragma unroll
    for (int i = 0; i < 4; i++) {
      int id = i * 256 + tid;
      int row = id >> 3, coff = (id & 7) * 8;
      gload_lds16(Ab + (size_t)(bm * 128 + row) * F_DIM + f0 + coff, &As[id * 8]);
      gload_lds16(Bb + (size_t)(bn * 128 + row) * F_DIM + f0 + coff, &Bs[id * 8]);
    }
    __syncthreads();
    #pragma unroll
    for (int kk = 0; kk < 64; kk += 32) {
      bf16x8 af[4], bfr[4];
      #pragma unroll
      for (int m = 0; m < 4; m++)
        af[m] = *(const bf16x8*)&As[(wm * 64 + m * 16 + (lane & 15)) * 64 + kk + (lane >> 4) * 8];
      #pragma unroll
      for (int n = 0; n < 4; n++)
        bfr[n] = *(const bf16x8*)&Bs[(wn * 64 + n * 16 + (lane & 15)) * 64 + kk + (lane >> 4) * 8];
      #pragma unroll
      for (int m = 0; m < 4; m++)
        #pragma unroll
        for (int n = 0; n < 4; n++)
          acc[m][n] = __builtin_amdgcn_mfma_f32_16x16x32_bf16(af[m], bfr[n], acc[m][n], 0, 0, 0);
    }
    __syncthreads();
  }

  // epilogue: out = acc + sum_e gates[t][e]*eb2[e][d] + sb2[0][d] + sb2[1][d]
  float sb2c[4];
  float eb2c[4][NE];
  #pragma unroll
  for (int n = 0; n < 4; n++) {
    int col = bn * 128 + wn * 64 + n * 16 + (lane & 15);
    sb2c[n] = sb2[col] + sb2[D_DIM + col];
    #pragma unroll
    for (int e = 0; e < NE; e++) eb2c[n][e] = eb2[(size_t)e * D_DIM + col];
  }
  #pragma unroll
  for (int m = 0; m < 4; m++) {
    #pragma unroll
    for (int r = 0; r < 4; r++) {
      int row = bm * 128 + wm * 64 + m * 16 + (lane >> 4) * 4 + r;
      float grv[NE];
      #pragma unroll
      for (int e = 0; e < NE; e++) grv[e] = gates[row * NE + e];
      #pragma unroll
      for (int n = 0; n < 4; n++) {
        int col = bn * 128 + wn * 64 + n * 16 + (lane & 15);
        float v = acc[m][n][r] + sb2c[n];
        #pragma unroll
        for (int e = 0; e < NE; e++) v += grv[e] * eb2c[n][e];
        out[(size_t)row * D_DIM + col] = v;
      }
    }
  }
}

// ---------------------------------------------------------------------------
extern "C" void kernel_launch(void* const* d_in, const int* in_sizes, int n_in,
                              void* d_out, int out_size, void* d_ws, size_t ws_size,
                              hipStream_t stream) {
  (void)in_sizes; (void)n_in; (void)out_size; (void)ws_size;
  const float* x        = (const float*)d_in[0];
  const float* router_w = (const float*)d_in[1];
  const float* router_b = (const float*)d_in[2];
  const float* ew1      = (const float*)d_in[3];
  const float* eb1      = (const float*)d_in[4];
  const float* ew2      = (const float*)d_in[5];
  const float* eb2      = (const float*)d_in[6];
  const float* sw1      = (const float*)d_in[7];
  const float* sb1      = (const float*)d_in[8];
  const float* sw2      = (const float*)d_in[9];
  const float* sb2      = (const float*)d_in[10];
  float* out = (float*)d_out;

  // workspace layout (bytes):
  //   xb   : 0            bf16 [8192][2048]           33,554,432 B
  //   w1t  : +33,554,432  bf16 [10][512][2048]        20,971,520 B
  //   w2t  : +54,525,952  bf16 [10][2048][512]        20,971,520 B
  //   H    : +75,497,472  bf16 [10][8192][512]        83,886,080 B
  //   gates: +159,383,552 f32  [8192][8]                 262,144 B
  //   counts:+159,645,696 u32  [2]
  char* ws = (char*)d_ws;
  short*    xb     = (short*)ws;
  short*    w1t    = xb + (size_t)TOKENS * D_DIM;
  short*    w2t    = w1t + (size_t)NZ * F_DIM * D_DIM;
  short*    Hbuf   = w2t + (size_t)NZ * D_DIM * F_DIM;
  float*    gates  = (float*)(Hbuf + (size_t)NZ * TOKENS * F_DIM);
  unsigned* counts = (unsigned*)(gates + (size_t)TOKENS * NE);

  // 1) convert x to bf16
  k_convert<<<2048, 256, 0, stream>>>(x, xb, TOKENS * D_DIM / 4);
  // 2) transpose-convert weights: w1t[z] = ew1[z]^T (F,D); w2t[z] = ew2[z]^T (D,F)
  k_transpose<<<dim3(F_DIM / 32, D_DIM / 32, NE),  dim3(32, 8), 0, stream>>>(ew1, w1t, D_DIM, F_DIM);
  k_transpose<<<dim3(F_DIM / 32, D_DIM / 32, NSH), dim3(32, 8), 0, stream>>>(sw1, w1t + (size_t)NE * F_DIM * D_DIM, D_DIM, F_DIM);
  k_transpose<<<dim3(D_DIM / 32, F_DIM / 32, NE),  dim3(32, 8), 0, stream>>>(ew2, w2t, F_DIM, D_DIM);
  k_transpose<<<dim3(D_DIM / 32, F_DIM / 32, NSH), dim3(32, 8), 0, stream>>>(sw2, w2t + (size_t)NE * D_DIM * F_DIM, F_DIM, D_DIM);
  // 3) router
  k_init<<<1, 64, 0, stream>>>(counts);
  k_router<<<TOKENS / 4, 256, 0, stream>>>(x, router_w, router_b, gates, counts);
  k_loss<<<1, 64, 0, stream>>>(counts, out + OUT_ELEMS);
  // 4) FFN
  k_gemm1<<<dim3(TOKENS / 128, F_DIM / 128, NZ), 256, 0, stream>>>(xb, w1t, eb1, sb1, gates, Hbuf);
  k_gemm2<<<dim3(TOKENS / 128, D_DIM / 128), 256, 0, stream>>>(Hbuf, w2t, eb2, sb2, gates, out);
}